// Round 3
// baseline (749.612 us; speedup 1.0000x reference)
//
#include <hip/hip_runtime.h>
#include <hip/hip_bf16.h>
#include <math.h>

typedef __bf16 bf16;
typedef __bf16 bf16x8 __attribute__((ext_vector_type(8)));
typedef float f32x4 __attribute__((ext_vector_type(4)));

#define SCALE 0.125f

// ---------------- row LayerNorm: fp32 in -> bf16 out, one block per row of 1024 ----------------
__global__ __launch_bounds__(256) void ln_f32(const float* __restrict__ x,
                                              const float* __restrict__ g,
                                              const float* __restrict__ b,
                                              bf16* __restrict__ y) {
  long base = (long)blockIdx.x * 1024;
  int tid = threadIdx.x;
  float v[4];
#pragma unroll
  for (int i = 0; i < 4; i++) v[i] = x[base + tid + i * 256];
  float s1 = v[0] + v[1] + v[2] + v[3];
  float s2 = v[0] * v[0] + v[1] * v[1] + v[2] * v[2] + v[3] * v[3];
#pragma unroll
  for (int off = 32; off; off >>= 1) {
    s1 += __shfl_xor(s1, off);
    s2 += __shfl_xor(s2, off);
  }
  __shared__ float aux[2][4];
  int wave = tid >> 6, lane = tid & 63;
  if (lane == 0) { aux[0][wave] = s1; aux[1][wave] = s2; }
  __syncthreads();
  float S1 = aux[0][0] + aux[0][1] + aux[0][2] + aux[0][3];
  float S2 = aux[1][0] + aux[1][1] + aux[1][2] + aux[1][3];
  float mean = S1 * (1.0f / 1024.0f);
  float var = S2 * (1.0f / 1024.0f) - mean * mean;
  float rs = rsqrtf(var + 1e-5f);
#pragma unroll
  for (int i = 0; i < 4; i++) {
    int c = tid + i * 256;
    y[base + c] = (bf16)(((v[i] - mean) * rs) * g[c] + b[c]);
  }
}

// ------- softmax over rows of 1024 (bf16 in/out), folds BOTH scale factors -------
__global__ __launch_bounds__(256) void softmax_rows(bf16* __restrict__ S) {
  long base = (long)blockIdx.x * 1024;
  int tid = threadIdx.x;
  float v[4];
#pragma unroll
  for (int i = 0; i < 4; i++) v[i] = (float)S[base + tid + i * 256] * SCALE;
  float m = fmaxf(fmaxf(v[0], v[1]), fmaxf(v[2], v[3]));
#pragma unroll
  for (int off = 32; off; off >>= 1) m = fmaxf(m, __shfl_xor(m, off));
  __shared__ float auxm[4];
  __shared__ float auxs[4];
  int wave = tid >> 6, lane = tid & 63;
  if (lane == 0) auxm[wave] = m;
  __syncthreads();
  float M = fmaxf(fmaxf(auxm[0], auxm[1]), fmaxf(auxm[2], auxm[3]));
  float e[4];
  float s = 0.0f;
#pragma unroll
  for (int i = 0; i < 4; i++) { e[i] = expf(v[i] - M); s += e[i]; }
#pragma unroll
  for (int off = 32; off; off >>= 1) s += __shfl_xor(s, off);
  if (lane == 0) auxs[wave] = s;
  __syncthreads();
  float SUM = auxs[0] + auxs[1] + auxs[2] + auxs[3];
  float sc = SCALE / SUM;  // second SCALE (faithful to reference) folded here
#pragma unroll
  for (int i = 0; i < 4; i++) S[base + tid + i * 256] = (bf16)(e[i] * sc);
}

// ---------------- W[K][N] fp32 -> Wt[N][K] bf16 tiled transpose ----------------
__global__ __launch_bounds__(256) void transpose_w(const float* __restrict__ W,
                                                   bf16* __restrict__ Wt,
                                                   int K, int N) {
  __shared__ bf16 tile[64][66];
  int n0 = blockIdx.x * 64, k0 = blockIdx.y * 64;
  int c = threadIdx.x & 63, r4 = threadIdx.x >> 6;
#pragma unroll
  for (int i = 0; i < 16; i++)
    tile[i * 4 + r4][c] = (bf16)W[(long)(k0 + i * 4 + r4) * N + n0 + c];
  __syncthreads();
#pragma unroll
  for (int i = 0; i < 16; i++)
    Wt[(long)(n0 + i * 4 + r4) * K + k0 + c] = tile[c][i * 4 + r4];
}

// ------- extract V^T per (b,h): Vt[bh][d][n] = KV[b*1024+n][1024 + h*64 + d] (bf16) -------
__global__ __launch_bounds__(256) void extract_vt(const bf16* __restrict__ KV,
                                                  bf16* __restrict__ Vt) {
  __shared__ bf16 tile[64][66];
  int bh = blockIdx.z, b = bh >> 4, h = bh & 15;
  const bf16* src = KV + (long)b * 1024 * 2048 + 1024 + h * 64;
  bf16* dst = Vt + (long)bh * 64 * 1024;
  int n0 = blockIdx.x * 64;
  int c = threadIdx.x & 63, r4 = threadIdx.x >> 6;
#pragma unroll
  for (int i = 0; i < 16; i++)
    tile[i * 4 + r4][c] = src[(long)(n0 + i * 4 + r4) * 2048 + c];
  __syncthreads();
#pragma unroll
  for (int i = 0; i < 16; i++)
    dst[(long)(i * 4 + r4) * 1024 + n0 + c] = tile[c][i * 4 + r4];
}

// ---------------- C = A @ Bt^T (+epilogue). A[M,K] bf16, Bt[N,K] bf16, batched via z -------
// epi: 0 = store C (bf16)
//      1 = acc + bias(f32) + res -> store  (res fp32 if res_bf16==0 else bf16; C fp32 if c_fp32)
//      2 = gelu(acc + bias(f32)) -> store C (bf16)
#define BM 128
#define BN 128
#define BK 32
__global__ __launch_bounds__(256) void gemm_bt(
    const bf16* __restrict__ A, long sA, int lda,
    const bf16* __restrict__ B, long sB, int ldb,
    void* __restrict__ Cv, long sC, int ldc,
    int M, int N, int K, int epi, int c_fp32,
    const float* __restrict__ bias,
    const void* __restrict__ resv, int ldr, int res_bf16) {
  __shared__ __align__(16) bf16 As[BM * BK];
  __shared__ __align__(16) bf16 Bs[BN * BK];
  int tid = threadIdx.x;
  int wave = tid >> 6, lane = tid & 63;
  int wm = wave >> 1, wn = wave & 1;
  int quad = lane >> 4, l16 = lane & 15;
  const bf16* Ab = A + (long)blockIdx.z * sA;
  const bf16* Bb = B + (long)blockIdx.z * sB;
  int m0 = blockIdx.y * BM, n0 = blockIdx.x * BN;

  f32x4 acc[4][4] = {};

  int r_a = tid >> 2;        // 0..63
  int c_a = (tid & 3) << 3;  // 0,8,16,24

  for (int kt = 0; kt < K; kt += BK) {
    __syncthreads();
    {
      int r0 = r_a, r1 = r_a + 64;
      *(bf16x8*)&As[r0 * BK + c_a] =
          *(const bf16x8*)&Ab[(long)(m0 + r0) * lda + kt + c_a];
      *(bf16x8*)&As[r1 * BK + c_a] =
          *(const bf16x8*)&Ab[(long)(m0 + r1) * lda + kt + c_a];
      int g0 = n0 + r0; if (g0 >= N) g0 = N - 1;  // N=64 (PV) guard
      int g1 = n0 + r1; if (g1 >= N) g1 = N - 1;
      *(bf16x8*)&Bs[r0 * BK + c_a] =
          *(const bf16x8*)&Bb[(long)g0 * ldb + kt + c_a];
      *(bf16x8*)&Bs[r1 * BK + c_a] =
          *(const bf16x8*)&Bb[(long)g1 * ldb + kt + c_a];
    }
    __syncthreads();
    bf16x8 af[4], bfr[4];
#pragma unroll
    for (int mt = 0; mt < 4; mt++)
      af[mt] = *(const bf16x8*)&As[(wm * 64 + mt * 16 + l16) * BK + quad * 8];
#pragma unroll
    for (int nt = 0; nt < 4; nt++)
      bfr[nt] = *(const bf16x8*)&Bs[(wn * 64 + nt * 16 + l16) * BK + quad * 8];
#pragma unroll
    for (int mt = 0; mt < 4; mt++)
#pragma unroll
      for (int nt = 0; nt < 4; nt++)
        acc[mt][nt] = __builtin_amdgcn_mfma_f32_16x16x32_bf16(
            af[mt], bfr[nt], acc[mt][nt], 0, 0, 0);
  }

  int gm = m0 + wm * 64, gn = n0 + wn * 64;
#pragma unroll
  for (int nt = 0; nt < 4; nt++) {
    int col = gn + nt * 16 + l16;
    if (col >= N) continue;
    float bv = (epi != 0) ? bias[col] : 0.0f;
#pragma unroll
    for (int mt = 0; mt < 4; mt++) {
#pragma unroll
      for (int r = 0; r < 4; r++) {
        int row = gm + mt * 16 + quad * 4 + r;
        float v = acc[mt][nt][r] + bv;
        if (epi == 2) {
          v = 0.5f * v * (1.0f + erff(v * 0.70710678118654752f));
        } else if (epi == 1) {
          float rv = res_bf16 ? (float)((const bf16*)resv)[(long)row * ldr + col]
                              : ((const float*)resv)[(long)row * ldr + col];
          v += rv;
        }
        if (c_fp32)
          ((float*)Cv)[(long)blockIdx.z * sC + (long)row * ldc + col] = v;
        else
          ((bf16*)Cv)[(long)blockIdx.z * sC + (long)row * ldc + col] = (bf16)v;
      }
    }
  }
}

extern "C" void kernel_launch(void* const* d_in, const int* in_sizes, int n_in,
                              void* d_out, int out_size, void* d_ws, size_t ws_size,
                              hipStream_t stream) {
  const float* src_q  = (const float*)d_in[0];
  const float* src_kv = (const float*)d_in[1];
  const float* gq     = (const float*)d_in[2];
  const float* bq     = (const float*)d_in[3];
  const float* gkv    = (const float*)d_in[4];
  const float* bkv    = (const float*)d_in[5];
  const float* Wq     = (const float*)d_in[6];
  const float* Wkv    = (const float*)d_in[7];
  const float* Wproj  = (const float*)d_in[8];
  const float* bproj  = (const float*)d_in[9];
  const float* gn     = (const float*)d_in[10];
  const float* bn     = (const float*)d_in[11];
  const float* W1     = (const float*)d_in[12];
  const float* b1     = (const float*)d_in[13];
  const float* W2     = (const float*)d_in[14];
  const float* b2     = (const float*)d_in[15];
  float* out = (float*)d_out;

  char* ws = (char*)d_ws;
  const long MB = 1024 * 1024;
  // liveness-based layout, peak 104MB (round-1 ran a 160MB layout without fault -> ws_size >= 160MB)
  bf16* Wq_t    = (bf16*)(ws + 0 * MB);    // [1024][1024]  2MB   (whole run)
  bf16* Wkv_t   = (bf16*)(ws + 2 * MB);    // [2048][1024]  4MB
  bf16* Wproj_t = (bf16*)(ws + 6 * MB);    // [1024][1024]  2MB
  bf16* W1_t    = (bf16*)(ws + 8 * MB);    // [4096][1024]  8MB
  bf16* W2_t    = (bf16*)(ws + 16 * MB);   // [1024][4096]  8MB  (ld = 4096!)
  bf16* qn      = (bf16*)(ws + 24 * MB);   // [4096][1024]  8MB   dead after Q GEMM
  bf16* kvn     = (bf16*)(ws + 32 * MB);   // [4096][1024]  8MB   dead after KV GEMM
  bf16* Qm      = (bf16*)(ws + 40 * MB);   // [4096][1024]  8MB   dead after last S GEMM
  bf16* KVm     = (bf16*)(ws + 48 * MB);   // [4096][2048] 16MB   dead after last S GEMM
  bf16* Vt      = (bf16*)(ws + 64 * MB);   // [64][64][1024] 8MB  dead after last PV GEMM
  bf16* Sbuf    = (bf16*)(ws + 72 * MB);   // 16x[1024][1024] 32MB per-b chunk, dead after attn
  bf16* xbuf    = (bf16*)(ws + 24 * MB);   // [4096][1024]  8MB   (reuses qn)
  float* tbuf   = (float*)(ws + 48 * MB);  // [4096][1024] 16MB fp32 (reuses KVm)
  bf16* sbuf    = (bf16*)(ws + 64 * MB);   // [4096][1024]  8MB   (reuses Vt)
  bf16* hbuf    = (bf16*)(ws + 72 * MB);   // [4096][4096] 32MB   (reuses Sbuf)

  // weight transposes (fp32 -> bf16)
  transpose_w<<<dim3(16, 16), 256, 0, stream>>>(Wq, Wq_t, 1024, 1024);
  transpose_w<<<dim3(32, 16), 256, 0, stream>>>(Wkv, Wkv_t, 1024, 2048);
  transpose_w<<<dim3(16, 16), 256, 0, stream>>>(Wproj, Wproj_t, 1024, 1024);
  transpose_w<<<dim3(64, 16), 256, 0, stream>>>(W1, W1_t, 1024, 4096);
  transpose_w<<<dim3(16, 64), 256, 0, stream>>>(W2, W2_t, 4096, 1024);

  // LayerNorms (fp32 -> bf16)
  ln_f32<<<4096, 256, 0, stream>>>(src_q, gq, bq, qn);
  ln_f32<<<4096, 256, 0, stream>>>(src_kv, gkv, bkv, kvn);

  // Q = qn @ Wq ; KV = kvn @ Wkv   (bf16 out)
  gemm_bt<<<dim3(8, 32, 1), 256, 0, stream>>>(qn, 0, 1024, Wq_t, 0, 1024,
                                              Qm, 0, 1024, 4096, 1024, 1024,
                                              0, 0, nullptr, nullptr, 0, 0);
  gemm_bt<<<dim3(16, 32, 1), 256, 0, stream>>>(kvn, 0, 1024, Wkv_t, 0, 1024,
                                               KVm, 0, 2048, 4096, 2048, 1024,
                                               0, 0, nullptr, nullptr, 0, 0);
  extract_vt<<<dim3(16, 1, 64), 256, 0, stream>>>(KVm, Vt);

  // attention, chunked per batch b (16 heads share Sbuf)
  for (int b = 0; b < 4; b++) {
    // S_bh = Q_bh @ K_bh^T  (K rows are [n][d] == Bt layout)
    gemm_bt<<<dim3(8, 8, 16), 256, 0, stream>>>(
        Qm + (long)b * 1048576, 64, 1024,
        KVm + (long)b * 2097152, 64, 2048,
        Sbuf, 1048576, 1024,
        1024, 1024, 64, 0, 0, nullptr, nullptr, 0, 0);
    softmax_rows<<<16384, 256, 0, stream>>>(Sbuf);
    // x_bh = P_bh @ V_bh   (Bt = V^T)
    gemm_bt<<<dim3(1, 8, 16), 256, 0, stream>>>(
        Sbuf, 1048576, 1024,
        Vt + (long)b * 1048576, 65536, 1024,
        xbuf + (long)b * 1048576, 64, 1024,
        1024, 64, 1024, 0, 0, nullptr, nullptr, 0, 0);
  }

  // tbuf = src_q + x @ Wproj + bproj   (fp32 out)
  gemm_bt<<<dim3(8, 32, 1), 256, 0, stream>>>(xbuf, 0, 1024, Wproj_t, 0, 1024,
                                              tbuf, 0, 1024, 4096, 1024, 1024,
                                              1, 1, bproj, src_q, 1024, 0);
  // sbuf = LN(tbuf)  (bf16 out)
  ln_f32<<<4096, 256, 0, stream>>>(tbuf, gn, bn, sbuf);
  // hbuf = gelu(sbuf @ W1 + b1)  (bf16 out)
  gemm_bt<<<dim3(32, 32, 1), 256, 0, stream>>>(sbuf, 0, 1024, W1_t, 0, 1024,
                                               hbuf, 0, 4096, 4096, 4096, 1024,
                                               2, 0, b1, nullptr, 0, 0);
  // out = sbuf + hbuf @ W2 + b2  (fp32 out)  [FIX: ldb 1024 -> 4096, W2_t rows are K=4096 long]
  gemm_bt<<<dim3(8, 32, 1), 256, 0, stream>>>(hbuf, 0, 4096, W2_t, 0, 4096,
                                              out, 0, 1024, 4096, 1024, 4096,
                                              1, 1, b2, sbuf, 1024, 1);
}

// Round 4
// 663.581 us; speedup vs baseline: 1.1296x; 1.1296x over previous
//
#include <hip/hip_runtime.h>
#include <hip/hip_bf16.h>
#include <math.h>

typedef __bf16 bf16;
typedef __bf16 bf16x8 __attribute__((ext_vector_type(8)));
typedef float f32x4 __attribute__((ext_vector_type(4)));

#define SCALE 0.125f

// async global->LDS, 16B per lane. LDS dest must be wave-uniform base + lane*16.
#define GLOAD_LDS16(gptr, lptr)                                      \
  __builtin_amdgcn_global_load_lds(                                  \
      (const __attribute__((address_space(1))) void*)(gptr),         \
      (__attribute__((address_space(3))) void*)(lptr), 16, 0, 0)

// ---------------- row LayerNorm: fp32 in -> bf16 out, one block per row of 1024 ----------------
__global__ __launch_bounds__(256) void ln_f32(const float* __restrict__ x,
                                              const float* __restrict__ g,
                                              const float* __restrict__ b,
                                              bf16* __restrict__ y) {
  long base = (long)blockIdx.x * 1024;
  int tid = threadIdx.x;
  float v[4];
#pragma unroll
  for (int i = 0; i < 4; i++) v[i] = x[base + tid + i * 256];
  float s1 = v[0] + v[1] + v[2] + v[3];
  float s2 = v[0] * v[0] + v[1] * v[1] + v[2] * v[2] + v[3] * v[3];
#pragma unroll
  for (int off = 32; off; off >>= 1) {
    s1 += __shfl_xor(s1, off);
    s2 += __shfl_xor(s2, off);
  }
  __shared__ float aux[2][4];
  int wave = tid >> 6, lane = tid & 63;
  if (lane == 0) { aux[0][wave] = s1; aux[1][wave] = s2; }
  __syncthreads();
  float S1 = aux[0][0] + aux[0][1] + aux[0][2] + aux[0][3];
  float S2 = aux[1][0] + aux[1][1] + aux[1][2] + aux[1][3];
  float mean = S1 * (1.0f / 1024.0f);
  float var = S2 * (1.0f / 1024.0f) - mean * mean;
  float rs = rsqrtf(var + 1e-5f);
#pragma unroll
  for (int i = 0; i < 4; i++) {
    int c = tid + i * 256;
    y[base + c] = (bf16)(((v[i] - mean) * rs) * g[c] + b[c]);
  }
}

// ------- softmax over rows of 1024 (bf16 in/out), folds BOTH scale factors -------
__global__ __launch_bounds__(256) void softmax_rows(bf16* __restrict__ S) {
  long base = (long)blockIdx.x * 1024;
  int tid = threadIdx.x;
  float v[4];
#pragma unroll
  for (int i = 0; i < 4; i++) v[i] = (float)S[base + tid + i * 256] * SCALE;
  float m = fmaxf(fmaxf(v[0], v[1]), fmaxf(v[2], v[3]));
#pragma unroll
  for (int off = 32; off; off >>= 1) m = fmaxf(m, __shfl_xor(m, off));
  __shared__ float auxm[4];
  __shared__ float auxs[4];
  int wave = tid >> 6, lane = tid & 63;
  if (lane == 0) auxm[wave] = m;
  __syncthreads();
  float M = fmaxf(fmaxf(auxm[0], auxm[1]), fmaxf(auxm[2], auxm[3]));
  float e[4];
  float s = 0.0f;
#pragma unroll
  for (int i = 0; i < 4; i++) { e[i] = expf(v[i] - M); s += e[i]; }
#pragma unroll
  for (int off = 32; off; off >>= 1) s += __shfl_xor(s, off);
  if (lane == 0) auxs[wave] = s;
  __syncthreads();
  float SUM = auxs[0] + auxs[1] + auxs[2] + auxs[3];
  float sc = SCALE / SUM;  // second SCALE (faithful to reference) folded here
#pragma unroll
  for (int i = 0; i < 4; i++) S[base + tid + i * 256] = (bf16)(e[i] * sc);
}

// ---------------- W[K][N] fp32 -> Wt[N][K] bf16 tiled transpose ----------------
__global__ __launch_bounds__(256) void transpose_w(const float* __restrict__ W,
                                                   bf16* __restrict__ Wt,
                                                   int K, int N) {
  __shared__ bf16 tile[64][66];
  int n0 = blockIdx.x * 64, k0 = blockIdx.y * 64;
  int c = threadIdx.x & 63, r4 = threadIdx.x >> 6;
#pragma unroll
  for (int i = 0; i < 16; i++)
    tile[i * 4 + r4][c] = (bf16)W[(long)(k0 + i * 4 + r4) * N + n0 + c];
  __syncthreads();
#pragma unroll
  for (int i = 0; i < 16; i++)
    Wt[(long)(n0 + i * 4 + r4) * K + k0 + c] = tile[c][i * 4 + r4];
}

// ------- extract V^T per (b,h): Vt[bh][d][n] = KV[b*1024+n][1024 + h*64 + d] (bf16) -------
__global__ __launch_bounds__(256) void extract_vt(const bf16* __restrict__ KV,
                                                  bf16* __restrict__ Vt) {
  __shared__ bf16 tile[64][66];
  int bh = blockIdx.z, b = bh >> 4, h = bh & 15;
  const bf16* src = KV + (long)b * 1024 * 2048 + 1024 + h * 64;
  bf16* dst = Vt + (long)bh * 64 * 1024;
  int n0 = blockIdx.x * 64;
  int c = threadIdx.x & 63, r4 = threadIdx.x >> 6;
#pragma unroll
  for (int i = 0; i < 16; i++)
    tile[i * 4 + r4][c] = src[(long)(n0 + i * 4 + r4) * 2048 + c];
  __syncthreads();
#pragma unroll
  for (int i = 0; i < 16; i++)
    dst[(long)(i * 4 + r4) * 1024 + n0 + c] = tile[c][i * 4 + r4];
}

// ---------------- C = A @ Bt^T (+epilogue). A[M,K] bf16, Bt[N,K] bf16 -------------
// z decomposed as (z>>4, z&15) with separate hi/lo strides per pointer
// (uniform-stride launches pass hi = 16*lo; z=0 launches pass 0,0).
// epi: 0 = store C (bf16)
//      1 = acc + bias(f32) + res -> store  (res fp32 if res_bf16==0 else bf16; C fp32 if c_fp32)
//      2 = gelu(acc + bias(f32)) -> store C (bf16)
#define BM 128
#define BN 128
#define BK 32
__global__ __launch_bounds__(256) void gemm_bt(
    const bf16* __restrict__ A, long sA_lo, long sA_hi, int lda,
    const bf16* __restrict__ B, long sB_lo, long sB_hi, int ldb,
    void* __restrict__ Cv, long sC_lo, long sC_hi, int ldc,
    int M, int N, int K, int epi, int c_fp32,
    const float* __restrict__ bias,
    const void* __restrict__ resv, int ldr, int res_bf16) {
  __shared__ __align__(16) bf16 As[BM * BK];
  __shared__ __align__(16) bf16 Bs[BN * BK];
  int tid = threadIdx.x;
  int wave = tid >> 6, lane = tid & 63;
  int wm = wave >> 1, wn = wave & 1;
  int quad = lane >> 4, l16 = lane & 15;
  int zhi = blockIdx.z >> 4, zlo = blockIdx.z & 15;
  const bf16* Ab = A + zhi * sA_hi + zlo * sA_lo;
  const bf16* Bb = B + zhi * sB_hi + zlo * sB_lo;
  long coff = zhi * sC_hi + zlo * sC_lo;
  int m0 = blockIdx.y * BM, n0 = blockIdx.x * BN;

  f32x4 acc[4][4] = {};

  // staging map: wave w stages rows [w*32, w*32+32) of the 128-row tile;
  // lane l -> row w*32 + (l>>2) (+16), col8 = (l&3)*8.  LDS bytes land at
  // w*2048 + l*16 (+1024) -- contiguous in lane order (global_load_lds req).
  int rsub = lane >> 2;          // 0..15
  int csub = (lane & 3) << 3;    // 0,8,16,24
  int ra0 = wave * 32 + rsub;
  int ra1 = ra0 + 16;
  int gb0 = n0 + ra0; if (gb0 >= N) gb0 = N - 1;  // N=64 (PV) guard
  int gb1 = n0 + ra1; if (gb1 >= N) gb1 = N - 1;

  for (int kt = 0; kt < K; kt += BK) {
    __syncthreads();
    GLOAD_LDS16(&Ab[(long)(m0 + ra0) * lda + kt + csub], &As[ra0 * BK + csub]);
    GLOAD_LDS16(&Ab[(long)(m0 + ra1) * lda + kt + csub], &As[ra1 * BK + csub]);
    GLOAD_LDS16(&Bb[(long)gb0 * ldb + kt + csub], &Bs[ra0 * BK + csub]);
    GLOAD_LDS16(&Bb[(long)gb1 * ldb + kt + csub], &Bs[ra1 * BK + csub]);
    __syncthreads();
    bf16x8 af[4], bfr[4];
#pragma unroll
    for (int mt = 0; mt < 4; mt++)
      af[mt] = *(const bf16x8*)&As[(wm * 64 + mt * 16 + l16) * BK + quad * 8];
#pragma unroll
    for (int nt = 0; nt < 4; nt++)
      bfr[nt] = *(const bf16x8*)&Bs[(wn * 64 + nt * 16 + l16) * BK + quad * 8];
#pragma unroll
    for (int mt = 0; mt < 4; mt++)
#pragma unroll
      for (int nt = 0; nt < 4; nt++)
        acc[mt][nt] = __builtin_amdgcn_mfma_f32_16x16x32_bf16(
            af[mt], bfr[nt], acc[mt][nt], 0, 0, 0);
  }

  int gm = m0 + wm * 64, gn = n0 + wn * 64;
#pragma unroll
  for (int nt = 0; nt < 4; nt++) {
    int col = gn + nt * 16 + l16;
    if (col >= N) continue;
    float bv = (epi != 0) ? bias[col] : 0.0f;
#pragma unroll
    for (int mt = 0; mt < 4; mt++) {
#pragma unroll
      for (int r = 0; r < 4; r++) {
        int row = gm + mt * 16 + quad * 4 + r;
        float v = acc[mt][nt][r] + bv;
        if (epi == 2) {
          v = 0.5f * v * (1.0f + erff(v * 0.70710678118654752f));
        } else if (epi == 1) {
          float rv = res_bf16 ? (float)((const bf16*)resv)[(long)row * ldr + col]
                              : ((const float*)resv)[(long)row * ldr + col];
          v += rv;
        }
        if (c_fp32)
          ((float*)Cv)[coff + (long)row * ldc + col] = v;
        else
          ((bf16*)Cv)[coff + (long)row * ldc + col] = (bf16)v;
      }
    }
  }
}

extern "C" void kernel_launch(void* const* d_in, const int* in_sizes, int n_in,
                              void* d_out, int out_size, void* d_ws, size_t ws_size,
                              hipStream_t stream) {
  const float* src_q  = (const float*)d_in[0];
  const float* src_kv = (const float*)d_in[1];
  const float* gq     = (const float*)d_in[2];
  const float* bq     = (const float*)d_in[3];
  const float* gkv    = (const float*)d_in[4];
  const float* bkv    = (const float*)d_in[5];
  const float* Wq     = (const float*)d_in[6];
  const float* Wkv    = (const float*)d_in[7];
  const float* Wproj  = (const float*)d_in[8];
  const float* bproj  = (const float*)d_in[9];
  const float* gn     = (const float*)d_in[10];
  const float* bn     = (const float*)d_in[11];
  const float* W1     = (const float*)d_in[12];
  const float* b1     = (const float*)d_in[13];
  const float* W2     = (const float*)d_in[14];
  const float* b2     = (const float*)d_in[15];
  float* out = (float*)d_out;

  char* ws = (char*)d_ws;
  const long MB = 1024 * 1024;
  // peak 136MB (round-1 ran a 160MB layout without fault -> ws_size >= 160MB)
  bf16* Wq_t    = (bf16*)(ws + 0 * MB);    // [1024][1024]  2MB   (whole run)
  bf16* Wkv_t   = (bf16*)(ws + 2 * MB);    // [2048][1024]  4MB
  bf16* Wproj_t = (bf16*)(ws + 6 * MB);    // [1024][1024]  2MB
  bf16* W1_t    = (bf16*)(ws + 8 * MB);    // [4096][1024]  8MB
  bf16* W2_t    = (bf16*)(ws + 16 * MB);   // [1024][4096]  8MB  (ld = 4096!)
  bf16* qn      = (bf16*)(ws + 24 * MB);   // [4096][1024]  8MB   dead after Q GEMM
  bf16* kvn     = (bf16*)(ws + 32 * MB);   // [4096][1024]  8MB   dead after KV GEMM
  bf16* Qm      = (bf16*)(ws + 40 * MB);   // [4096][1024]  8MB   dead after last S GEMM
  bf16* KVm     = (bf16*)(ws + 48 * MB);   // [4096][2048] 16MB   dead after last S GEMM
  bf16* Vt      = (bf16*)(ws + 64 * MB);   // [64][64][1024] 8MB  dead after last PV GEMM
  bf16* Sbuf    = (bf16*)(ws + 72 * MB);   // 32x[1024][1024] 64MB per 2-batch pair
  bf16* xbuf    = (bf16*)(ws + 24 * MB);   // [4096][1024]  8MB   (reuses qn)
  float* tbuf   = (float*)(ws + 48 * MB);  // [4096][1024] 16MB fp32 (reuses KVm)
  bf16* sbuf    = (bf16*)(ws + 64 * MB);   // [4096][1024]  8MB   (reuses Vt)
  bf16* hbuf    = (bf16*)(ws + 72 * MB);   // [4096][4096] 32MB   (reuses Sbuf)

  // weight transposes (fp32 -> bf16)
  transpose_w<<<dim3(16, 16), 256, 0, stream>>>(Wq, Wq_t, 1024, 1024);
  transpose_w<<<dim3(32, 16), 256, 0, stream>>>(Wkv, Wkv_t, 1024, 2048);
  transpose_w<<<dim3(16, 16), 256, 0, stream>>>(Wproj, Wproj_t, 1024, 1024);
  transpose_w<<<dim3(64, 16), 256, 0, stream>>>(W1, W1_t, 1024, 4096);
  transpose_w<<<dim3(16, 64), 256, 0, stream>>>(W2, W2_t, 4096, 1024);

  // LayerNorms (fp32 -> bf16)
  ln_f32<<<4096, 256, 0, stream>>>(src_q, gq, bq, qn);
  ln_f32<<<4096, 256, 0, stream>>>(src_kv, gkv, bkv, kvn);

  // Q = qn @ Wq ; KV = kvn @ Wkv   (bf16 out)
  gemm_bt<<<dim3(8, 32, 1), 256, 0, stream>>>(qn, 0, 0, 1024, Wq_t, 0, 0, 1024,
                                              Qm, 0, 0, 1024, 4096, 1024, 1024,
                                              0, 0, nullptr, nullptr, 0, 0);
  gemm_bt<<<dim3(16, 32, 1), 256, 0, stream>>>(kvn, 0, 0, 1024, Wkv_t, 0, 0, 1024,
                                               KVm, 0, 0, 2048, 4096, 2048, 1024,
                                               0, 0, nullptr, nullptr, 0, 0);
  extract_vt<<<dim3(16, 1, 64), 256, 0, stream>>>(KVm, Vt);

  // attention, 2 batches (32 heads) per chunk; z = b_local*16 + h
  for (int p = 0; p < 2; p++) {
    // S_bh = Q_bh @ K_bh^T  (K rows are [n][d] == Bt layout)
    gemm_bt<<<dim3(8, 8, 32), 256, 0, stream>>>(
        Qm + (long)p * 2097152, 64, 1048576, 1024,
        KVm + (long)p * 4194304, 64, 2097152, 2048,
        Sbuf, 1048576, 16777216, 1024,
        1024, 1024, 64, 0, 0, nullptr, nullptr, 0, 0);
    softmax_rows<<<32768, 256, 0, stream>>>(Sbuf);
    // x_bh = P_bh @ V_bh   (Bt = V^T)
    gemm_bt<<<dim3(1, 8, 32), 256, 0, stream>>>(
        Sbuf, 1048576, 16777216, 1024,
        Vt + (long)p * 2097152, 65536, 1048576, 1024,
        xbuf + (long)p * 2097152, 64, 1048576, 1024,
        1024, 64, 1024, 0, 0, nullptr, nullptr, 0, 0);
  }

  // tbuf = src_q + x @ Wproj + bproj   (fp32 out)
  gemm_bt<<<dim3(8, 32, 1), 256, 0, stream>>>(xbuf, 0, 0, 1024, Wproj_t, 0, 0, 1024,
                                              tbuf, 0, 0, 1024, 4096, 1024, 1024,
                                              1, 1, bproj, src_q, 1024, 0);
  // sbuf = LN(tbuf)  (bf16 out)
  ln_f32<<<4096, 256, 0, stream>>>(tbuf, gn, bn, sbuf);
  // hbuf = gelu(sbuf @ W1 + b1)  (bf16 out)
  gemm_bt<<<dim3(32, 32, 1), 256, 0, stream>>>(sbuf, 0, 0, 1024, W1_t, 0, 0, 1024,
                                               hbuf, 0, 0, 4096, 4096, 4096, 1024,
                                               2, 0, b1, nullptr, 0, 0);
  // out = sbuf + hbuf @ W2 + b2  (fp32 out)
  gemm_bt<<<dim3(8, 32, 1), 256, 0, stream>>>(hbuf, 0, 0, 4096, W2_t, 0, 0, 4096,
                                              out, 0, 0, 1024, 4096, 1024, 4096,
                                              1, 1, b2, sbuf, 1024, 1);
}

// Round 5
// 525.746 us; speedup vs baseline: 1.4258x; 1.2622x over previous
//
#include <hip/hip_runtime.h>
#include <hip/hip_bf16.h>
#include <math.h>

typedef __bf16 bf16;
typedef __bf16 bf16x8 __attribute__((ext_vector_type(8)));
typedef float f32x4 __attribute__((ext_vector_type(4)));

#define SCALE 0.125f

// async global->LDS, 16B per lane. LDS dest must be wave-uniform base + lane*16.
#define GLOAD_LDS16(gptr, lptr)                                      \
  __builtin_amdgcn_global_load_lds(                                  \
      (const __attribute__((address_space(1))) void*)(gptr),         \
      (__attribute__((address_space(3))) void*)(lptr), 16, 0, 0)

// ---------------- row LayerNorm: fp32 in -> bf16 out, one block per row of 1024 ----------------
__global__ __launch_bounds__(256) void ln_f32(const float* __restrict__ x,
                                              const float* __restrict__ g,
                                              const float* __restrict__ b,
                                              bf16* __restrict__ y) {
  long base = (long)blockIdx.x * 1024;
  int tid = threadIdx.x;
  float v[4];
#pragma unroll
  for (int i = 0; i < 4; i++) v[i] = x[base + tid + i * 256];
  float s1 = v[0] + v[1] + v[2] + v[3];
  float s2 = v[0] * v[0] + v[1] * v[1] + v[2] * v[2] + v[3] * v[3];
#pragma unroll
  for (int off = 32; off; off >>= 1) {
    s1 += __shfl_xor(s1, off);
    s2 += __shfl_xor(s2, off);
  }
  __shared__ float aux[2][4];
  int wave = tid >> 6, lane = tid & 63;
  if (lane == 0) { aux[0][wave] = s1; aux[1][wave] = s2; }
  __syncthreads();
  float S1 = aux[0][0] + aux[0][1] + aux[0][2] + aux[0][3];
  float S2 = aux[1][0] + aux[1][1] + aux[1][2] + aux[1][3];
  float mean = S1 * (1.0f / 1024.0f);
  float var = S2 * (1.0f / 1024.0f) - mean * mean;
  float rs = rsqrtf(var + 1e-5f);
#pragma unroll
  for (int i = 0; i < 4; i++) {
    int c = tid + i * 256;
    y[base + c] = (bf16)(((v[i] - mean) * rs) * g[c] + b[c]);
  }
}

// ------- softmax over rows of 1024 (bf16 in/out), folds BOTH scale factors -------
__global__ __launch_bounds__(256) void softmax_rows(bf16* __restrict__ S) {
  long base = (long)blockIdx.x * 1024;
  int tid = threadIdx.x;
  float v[4];
#pragma unroll
  for (int i = 0; i < 4; i++) v[i] = (float)S[base + tid + i * 256] * SCALE;
  float m = fmaxf(fmaxf(v[0], v[1]), fmaxf(v[2], v[3]));
#pragma unroll
  for (int off = 32; off; off >>= 1) m = fmaxf(m, __shfl_xor(m, off));
  __shared__ float auxm[4];
  __shared__ float auxs[4];
  int wave = tid >> 6, lane = tid & 63;
  if (lane == 0) auxm[wave] = m;
  __syncthreads();
  float M = fmaxf(fmaxf(auxm[0], auxm[1]), fmaxf(auxm[2], auxm[3]));
  float e[4];
  float s = 0.0f;
#pragma unroll
  for (int i = 0; i < 4; i++) { e[i] = expf(v[i] - M); s += e[i]; }
#pragma unroll
  for (int off = 32; off; off >>= 1) s += __shfl_xor(s, off);
  if (lane == 0) auxs[wave] = s;
  __syncthreads();
  float SUM = auxs[0] + auxs[1] + auxs[2] + auxs[3];
  float sc = SCALE / SUM;  // second SCALE (faithful to reference) folded here
#pragma unroll
  for (int i = 0; i < 4; i++) S[base + tid + i * 256] = (bf16)(e[i] * sc);
}

// ---------------- W[K][N] fp32 -> Wt[N][K] bf16 tiled transpose ----------------
__global__ __launch_bounds__(256) void transpose_w(const float* __restrict__ W,
                                                   bf16* __restrict__ Wt,
                                                   int K, int N) {
  __shared__ bf16 tile[64][66];
  int n0 = blockIdx.x * 64, k0 = blockIdx.y * 64;
  int c = threadIdx.x & 63, r4 = threadIdx.x >> 6;
#pragma unroll
  for (int i = 0; i < 16; i++)
    tile[i * 4 + r4][c] = (bf16)W[(long)(k0 + i * 4 + r4) * N + n0 + c];
  __syncthreads();
#pragma unroll
  for (int i = 0; i < 16; i++)
    Wt[(long)(n0 + i * 4 + r4) * K + k0 + c] = tile[c][i * 4 + r4];
}

// ------- extract V^T per (b,h): Vt[bh][d][n] = KV[b*1024+n][1024 + h*64 + d] (bf16) -------
__global__ __launch_bounds__(256) void extract_vt(const bf16* __restrict__ KV,
                                                  bf16* __restrict__ Vt) {
  __shared__ bf16 tile[64][66];
  int bh = blockIdx.z, b = bh >> 4, h = bh & 15;
  const bf16* src = KV + (long)b * 1024 * 2048 + 1024 + h * 64;
  bf16* dst = Vt + (long)bh * 64 * 1024;
  int n0 = blockIdx.x * 64;
  int c = threadIdx.x & 63, r4 = threadIdx.x >> 6;
#pragma unroll
  for (int i = 0; i < 16; i++)
    tile[i * 4 + r4][c] = src[(long)(n0 + i * 4 + r4) * 2048 + c];
  __syncthreads();
#pragma unroll
  for (int i = 0; i < 16; i++)
    dst[(long)(i * 4 + r4) * 1024 + n0 + c] = tile[c][i * 4 + r4];
}

// ---------------- templated C = A @ Bt^T (+epilogue) ----------------
// A[M,K] bf16 (lda), Bt[N,K] bf16 (ldb). z = (z>>4)*hi + (z&15)*lo strides.
// Wave grid WRxWC over the BMxBN tile; all tiles exact (no guards).
// EPI: 0 = store bf16; 1 = acc+bias+res (CF32 sets fp32 C; RBF16 sets bf16 res);
//      2 = gelu(acc+bias) -> bf16
template <int BM, int BN, int BK, int WR, int WC, int EPI, int CF32, int RBF16>
__global__ __launch_bounds__(256) void gemm_t(
    const bf16* __restrict__ A, long sA_lo, long sA_hi, int lda,
    const bf16* __restrict__ B, long sB_lo, long sB_hi, int ldb,
    void* __restrict__ Cv, long sC_lo, long sC_hi, int ldc,
    int K,
    const float* __restrict__ bias,
    const void* __restrict__ resv, int ldr) {
  constexpr int MT = BM / (16 * WR);
  constexpr int NT = BN / (16 * WC);
  constexpr int KS = BK / 32;
  constexpr int ACH = BM * BK / 2048;  // 16B staging chunks per thread (A)
  constexpr int BCH = BN * BK / 2048;  // 16B staging chunks per thread (B)
  __shared__ __align__(16) bf16 As[BM * BK];
  __shared__ __align__(16) bf16 Bs[BN * BK];
  int tid = threadIdx.x;
  int wave = tid >> 6, lane = tid & 63;
  int wm = wave / WC, wn = wave % WC;
  int quad = lane >> 4, l16 = lane & 15;
  int zhi = blockIdx.z >> 4, zlo = blockIdx.z & 15;
  const bf16* Ab = A + zhi * sA_hi + zlo * sA_lo;
  const bf16* Bb = B + zhi * sB_hi + zlo * sB_lo;
  long coff = zhi * sC_hi + zlo * sC_lo;
  int m0 = blockIdx.y * BM, n0 = blockIdx.x * BN;

  f32x4 acc[MT][NT] = {};

  for (int kt = 0; kt < K; kt += BK) {
    __syncthreads();
    // staging: instr t covers LDS elements [(t*256+tid)*8, +8) — LDS addr =
    // t*4096 + wave*1024 + lane*16 bytes = wave-uniform base + lane*16 (req).
#pragma unroll
    for (int t = 0; t < ACH; t++) {
      int eo = (t * 256 + tid) * 8;
      int r = eo / BK, c = eo % BK;
      GLOAD_LDS16(&Ab[(long)(m0 + r) * lda + kt + c], &As[eo]);
    }
#pragma unroll
    for (int t = 0; t < BCH; t++) {
      int eo = (t * 256 + tid) * 8;
      int r = eo / BK, c = eo % BK;
      GLOAD_LDS16(&Bb[(long)(n0 + r) * ldb + kt + c], &Bs[eo]);
    }
    __syncthreads();
    bf16x8 af[KS][MT], bfr[KS][NT];
#pragma unroll
    for (int ks = 0; ks < KS; ks++) {
#pragma unroll
      for (int mt = 0; mt < MT; mt++)
        af[ks][mt] = *(const bf16x8*)
            &As[(wm * MT * 16 + mt * 16 + l16) * BK + ks * 32 + quad * 8];
#pragma unroll
      for (int nt = 0; nt < NT; nt++)
        bfr[ks][nt] = *(const bf16x8*)
            &Bs[(wn * NT * 16 + nt * 16 + l16) * BK + ks * 32 + quad * 8];
    }
#pragma unroll
    for (int ks = 0; ks < KS; ks++)
#pragma unroll
      for (int mt = 0; mt < MT; mt++)
#pragma unroll
        for (int nt = 0; nt < NT; nt++)
          acc[mt][nt] = __builtin_amdgcn_mfma_f32_16x16x32_bf16(
              af[ks][mt], bfr[ks][nt], acc[mt][nt], 0, 0, 0);
  }

  int gm = m0 + wm * MT * 16, gn = n0 + wn * NT * 16;
#pragma unroll
  for (int nt = 0; nt < NT; nt++) {
    int col = gn + nt * 16 + l16;
    float bv = (EPI != 0) ? bias[col] : 0.0f;
#pragma unroll
    for (int mt = 0; mt < MT; mt++) {
#pragma unroll
      for (int r = 0; r < 4; r++) {
        int row = gm + mt * 16 + quad * 4 + r;
        float v = acc[mt][nt][r] + bv;
        if (EPI == 2) {
          v = 0.5f * v * (1.0f + erff(v * 0.70710678118654752f));
        } else if (EPI == 1) {
          float rv = RBF16 ? (float)((const bf16*)resv)[(long)row * ldr + col]
                           : ((const float*)resv)[(long)row * ldr + col];
          v += rv;
        }
        if (CF32)
          ((float*)Cv)[coff + (long)row * ldc + col] = v;
        else
          ((bf16*)Cv)[coff + (long)row * ldc + col] = (bf16)v;
      }
    }
  }
}

extern "C" void kernel_launch(void* const* d_in, const int* in_sizes, int n_in,
                              void* d_out, int out_size, void* d_ws, size_t ws_size,
                              hipStream_t stream) {
  const float* src_q  = (const float*)d_in[0];
  const float* src_kv = (const float*)d_in[1];
  const float* gq     = (const float*)d_in[2];
  const float* bq     = (const float*)d_in[3];
  const float* gkv    = (const float*)d_in[4];
  const float* bkv    = (const float*)d_in[5];
  const float* Wq     = (const float*)d_in[6];
  const float* Wkv    = (const float*)d_in[7];
  const float* Wproj  = (const float*)d_in[8];
  const float* bproj  = (const float*)d_in[9];
  const float* gn     = (const float*)d_in[10];
  const float* bn     = (const float*)d_in[11];
  const float* W1     = (const float*)d_in[12];
  const float* b1     = (const float*)d_in[13];
  const float* W2     = (const float*)d_in[14];
  const float* b2     = (const float*)d_in[15];
  float* out = (float*)d_out;

  char* ws = (char*)d_ws;
  const long MB = 1024 * 1024;
  // peak 136MB (round-1 ran a 160MB layout without fault -> ws_size >= 160MB)
  bf16* Wq_t    = (bf16*)(ws + 0 * MB);    // [1024][1024]  2MB   (whole run)
  bf16* Wkv_t   = (bf16*)(ws + 2 * MB);    // [2048][1024]  4MB
  bf16* Wproj_t = (bf16*)(ws + 6 * MB);    // [1024][1024]  2MB
  bf16* W1_t    = (bf16*)(ws + 8 * MB);    // [4096][1024]  8MB
  bf16* W2_t    = (bf16*)(ws + 16 * MB);   // [1024][4096]  8MB  (ld = 4096!)
  bf16* qn      = (bf16*)(ws + 24 * MB);   // [4096][1024]  8MB   dead after Q GEMM
  bf16* kvn     = (bf16*)(ws + 32 * MB);   // [4096][1024]  8MB   dead after KV GEMM
  bf16* Qm      = (bf16*)(ws + 40 * MB);   // [4096][1024]  8MB   dead after last S GEMM
  bf16* KVm     = (bf16*)(ws + 48 * MB);   // [4096][2048] 16MB   dead after last S GEMM
  bf16* Vt      = (bf16*)(ws + 64 * MB);   // [64][64][1024] 8MB  dead after last PV GEMM
  bf16* Sbuf    = (bf16*)(ws + 72 * MB);   // 32x[1024][1024] 64MB per 2-batch pair
  bf16* xbuf    = (bf16*)(ws + 24 * MB);   // [4096][1024]  8MB   (reuses qn)
  float* tbuf   = (float*)(ws + 48 * MB);  // [4096][1024] 16MB fp32 (reuses KVm)
  bf16* sbuf    = (bf16*)(ws + 64 * MB);   // [4096][1024]  8MB   (reuses Vt)
  bf16* hbuf    = (bf16*)(ws + 72 * MB);   // [4096][4096] 32MB   (reuses Sbuf)

  // weight transposes (fp32 -> bf16)
  transpose_w<<<dim3(16, 16), 256, 0, stream>>>(Wq, Wq_t, 1024, 1024);
  transpose_w<<<dim3(32, 16), 256, 0, stream>>>(Wkv, Wkv_t, 1024, 2048);
  transpose_w<<<dim3(16, 16), 256, 0, stream>>>(Wproj, Wproj_t, 1024, 1024);
  transpose_w<<<dim3(64, 16), 256, 0, stream>>>(W1, W1_t, 1024, 4096);
  transpose_w<<<dim3(16, 64), 256, 0, stream>>>(W2, W2_t, 4096, 1024);

  // LayerNorms (fp32 -> bf16)
  ln_f32<<<4096, 256, 0, stream>>>(src_q, gq, bq, qn);
  ln_f32<<<4096, 256, 0, stream>>>(src_kv, gkv, bkv, kvn);

  // Q = qn @ Wq   (N=1024 -> BN=64 config, 512 blocks)
  gemm_t<128, 64, 64, 4, 1, 0, 0, 0><<<dim3(16, 32, 1), 256, 0, stream>>>(
      qn, 0, 0, 1024, Wq_t, 0, 0, 1024, Qm, 0, 0, 1024, 1024,
      nullptr, nullptr, 0);
  // KV = kvn @ Wkv  (N=2048, 128x128 tiles, 512 blocks)
  gemm_t<128, 128, 64, 2, 2, 0, 0, 0><<<dim3(16, 32, 1), 256, 0, stream>>>(
      kvn, 0, 0, 1024, Wkv_t, 0, 0, 1024, KVm, 0, 0, 2048, 1024,
      nullptr, nullptr, 0);
  extract_vt<<<dim3(16, 1, 64), 256, 0, stream>>>(KVm, Vt);

  // attention, 2 batches (32 heads) per chunk; z = b_local*16 + h
  for (int p = 0; p < 2; p++) {
    // S_bh = Q_bh @ K_bh^T  (K=64: single K-iteration)
    gemm_t<128, 128, 64, 2, 2, 0, 0, 0><<<dim3(8, 8, 32), 256, 0, stream>>>(
        Qm + (long)p * 2097152, 64, 1048576, 1024,
        KVm + (long)p * 4194304, 64, 2097152, 2048,
        Sbuf, 1048576, 16777216, 1024, 64,
        nullptr, nullptr, 0);
    softmax_rows<<<32768, 256, 0, stream>>>(Sbuf);
    // x_bh = P_bh @ V_bh  (N=64 exact tile: BM=64,BN=64 -> 512 blocks, no waste)
    gemm_t<64, 64, 64, 4, 1, 0, 0, 0><<<dim3(1, 16, 32), 256, 0, stream>>>(
        Sbuf, 1048576, 16777216, 1024,
        Vt + (long)p * 2097152, 65536, 1048576, 1024,
        xbuf + (long)p * 2097152, 64, 1048576, 1024, 1024,
        nullptr, nullptr, 0);
  }

  // tbuf = src_q + x @ Wproj + bproj   (fp32 out, N=1024 -> BN=64)
  gemm_t<128, 64, 64, 4, 1, 1, 1, 0><<<dim3(16, 32, 1), 256, 0, stream>>>(
      xbuf, 0, 0, 1024, Wproj_t, 0, 0, 1024, tbuf, 0, 0, 1024, 1024,
      bproj, src_q, 1024);
  // sbuf = LN(tbuf)  (bf16 out)
  ln_f32<<<4096, 256, 0, stream>>>(tbuf, gn, bn, sbuf);
  // hbuf = gelu(sbuf @ W1 + b1)  (bf16 out, N=4096)
  gemm_t<128, 128, 64, 2, 2, 2, 0, 0><<<dim3(32, 32, 1), 256, 0, stream>>>(
      sbuf, 0, 0, 1024, W1_t, 0, 0, 1024, hbuf, 0, 0, 4096, 1024,
      b1, nullptr, 0);
  // out = sbuf + hbuf @ W2 + b2  (fp32 out, N=1024 -> BN=64, K=4096; ldb=4096)
  gemm_t<128, 64, 64, 4, 1, 1, 1, 1><<<dim3(16, 32, 1), 256, 0, stream>>>(
      hbuf, 0, 0, 4096, W2_t, 0, 0, 4096, out, 0, 0, 1024, 4096,
      b2, sbuf, 1024);
}

// Round 6
// 496.522 us; speedup vs baseline: 1.5097x; 1.0589x over previous
//
#include <hip/hip_runtime.h>
#include <hip/hip_bf16.h>
#include <math.h>

typedef __bf16 bf16;
typedef __bf16 bf16x8 __attribute__((ext_vector_type(8)));
typedef float f32x4 __attribute__((ext_vector_type(4)));

#define SCALE 0.125f

// async global->LDS, 16B per lane. LDS dest must be wave-uniform base + lane*16.
#define GLOAD_LDS16(gptr, lptr)                                      \
  __builtin_amdgcn_global_load_lds(                                  \
      (const __attribute__((address_space(1))) void*)(gptr),         \
      (__attribute__((address_space(3))) void*)(lptr), 16, 0, 0)

// ---------------- row LayerNorm: fp32 in -> bf16 out, one block per row of 1024 ----------------
__global__ __launch_bounds__(256) void ln_f32(const float* __restrict__ x,
                                              const float* __restrict__ g,
                                              const float* __restrict__ b,
                                              bf16* __restrict__ y) {
  long base = (long)blockIdx.x * 1024;
  int tid = threadIdx.x;
  float v[4];
#pragma unroll
  for (int i = 0; i < 4; i++) v[i] = x[base + tid + i * 256];
  float s1 = v[0] + v[1] + v[2] + v[3];
  float s2 = v[0] * v[0] + v[1] * v[1] + v[2] * v[2] + v[3] * v[3];
#pragma unroll
  for (int off = 32; off; off >>= 1) {
    s1 += __shfl_xor(s1, off);
    s2 += __shfl_xor(s2, off);
  }
  __shared__ float aux[2][4];
  int wave = tid >> 6, lane = tid & 63;
  if (lane == 0) { aux[0][wave] = s1; aux[1][wave] = s2; }
  __syncthreads();
  float S1 = aux[0][0] + aux[0][1] + aux[0][2] + aux[0][3];
  float S2 = aux[1][0] + aux[1][1] + aux[1][2] + aux[1][3];
  float mean = S1 * (1.0f / 1024.0f);
  float var = S2 * (1.0f / 1024.0f) - mean * mean;
  float rs = rsqrtf(var + 1e-5f);
#pragma unroll
  for (int i = 0; i < 4; i++) {
    int c = tid + i * 256;
    y[base + c] = (bf16)(((v[i] - mean) * rs) * g[c] + b[c]);
  }
}

// ------- softmax over rows of 1024 (bf16 in/out), folds BOTH scale factors -------
__global__ __launch_bounds__(256) void softmax_rows(bf16* __restrict__ S) {
  long base = (long)blockIdx.x * 1024;
  int tid = threadIdx.x;
  float v[4];
#pragma unroll
  for (int i = 0; i < 4; i++) v[i] = (float)S[base + tid + i * 256] * SCALE;
  float m = fmaxf(fmaxf(v[0], v[1]), fmaxf(v[2], v[3]));
#pragma unroll
  for (int off = 32; off; off >>= 1) m = fmaxf(m, __shfl_xor(m, off));
  __shared__ float auxm[4];
  __shared__ float auxs[4];
  int wave = tid >> 6, lane = tid & 63;
  if (lane == 0) auxm[wave] = m;
  __syncthreads();
  float M = fmaxf(fmaxf(auxm[0], auxm[1]), fmaxf(auxm[2], auxm[3]));
  float e[4];
  float s = 0.0f;
#pragma unroll
  for (int i = 0; i < 4; i++) { e[i] = expf(v[i] - M); s += e[i]; }
#pragma unroll
  for (int off = 32; off; off >>= 1) s += __shfl_xor(s, off);
  if (lane == 0) auxs[wave] = s;
  __syncthreads();
  float SUM = auxs[0] + auxs[1] + auxs[2] + auxs[3];
  float sc = SCALE / SUM;  // second SCALE (faithful to reference) folded here
#pragma unroll
  for (int i = 0; i < 4; i++) S[base + tid + i * 256] = (bf16)(e[i] * sc);
}

// ---------------- W[K][N] fp32 -> Wt[N][K] bf16 tiled transpose ----------------
__global__ __launch_bounds__(256) void transpose_w(const float* __restrict__ W,
                                                   bf16* __restrict__ Wt,
                                                   int K, int N) {
  __shared__ bf16 tile[64][66];
  int n0 = blockIdx.x * 64, k0 = blockIdx.y * 64;
  int c = threadIdx.x & 63, r4 = threadIdx.x >> 6;
#pragma unroll
  for (int i = 0; i < 16; i++)
    tile[i * 4 + r4][c] = (bf16)W[(long)(k0 + i * 4 + r4) * N + n0 + c];
  __syncthreads();
#pragma unroll
  for (int i = 0; i < 16; i++)
    Wt[(long)(n0 + i * 4 + r4) * K + k0 + c] = tile[c][i * 4 + r4];
}

// ------- extract V^T per (b,h): Vt[bh][d][n] = KV[b*1024+n][1024 + h*64 + d] (bf16) -------
__global__ __launch_bounds__(256) void extract_vt(const bf16* __restrict__ KV,
                                                  bf16* __restrict__ Vt) {
  __shared__ bf16 tile[64][66];
  int bh = blockIdx.z, b = bh >> 4, h = bh & 15;
  const bf16* src = KV + (long)b * 1024 * 2048 + 1024 + h * 64;
  bf16* dst = Vt + (long)bh * 64 * 1024;
  int n0 = blockIdx.x * 64;
  int c = threadIdx.x & 63, r4 = threadIdx.x >> 6;
#pragma unroll
  for (int i = 0; i < 16; i++)
    tile[i * 4 + r4][c] = src[(long)(n0 + i * 4 + r4) * 2048 + c];
  __syncthreads();
#pragma unroll
  for (int i = 0; i < 16; i++)
    dst[(long)(i * 4 + r4) * 1024 + n0 + c] = tile[c][i * 4 + r4];
}

// ---------------- templated C = A @ Bt^T (+epilogue) ----------------
// A[M,K] bf16 (lda), Bt[N,K] bf16 (ldb). z = (z>>4)*hi + (z&15)*lo strides.
// LDS uses an XOR-swizzled layout to kill ds_read_b128 bank conflicts:
// 16B chunk p of row r holds logical chunk (p ^ (r&7)).  (Padding is illegal
// with global_load_lds -- swizzle keeps the wave-uniform+lane*16 DMA layout.)
// EPI: 0 = store bf16; 1 = acc+bias+res (CF32 fp32 C; RBF16 bf16 res);
//      2 = gelu(acc+bias) -> bf16
template <int BM, int BN, int BK, int WR, int WC, int EPI, int CF32, int RBF16>
__global__ __launch_bounds__(256) void gemm_t(
    const bf16* __restrict__ A, long sA_lo, long sA_hi, int lda,
    const bf16* __restrict__ B, long sB_lo, long sB_hi, int ldb,
    void* __restrict__ Cv, long sC_lo, long sC_hi, int ldc,
    int K,
    const float* __restrict__ bias,
    const void* __restrict__ resv, int ldr) {
  constexpr int MT = BM / (16 * WR);
  constexpr int NT = BN / (16 * WC);
  constexpr int KS = BK / 32;
  constexpr int ACH = BM * BK / 2048;  // 16B staging chunks per thread (A)
  constexpr int BCH = BN * BK / 2048;  // 16B staging chunks per thread (B)
  __shared__ __align__(16) bf16 As[BM * BK];
  __shared__ __align__(16) bf16 Bs[BN * BK];
  int tid = threadIdx.x;
  int wave = tid >> 6, lane = tid & 63;
  int wm = wave / WC, wn = wave % WC;
  int quad = lane >> 4, l16 = lane & 15;
  int zhi = blockIdx.z >> 4, zlo = blockIdx.z & 15;
  const bf16* Ab = A + zhi * sA_hi + zlo * sA_lo;
  const bf16* Bb = B + zhi * sB_hi + zlo * sB_lo;
  long coff = zhi * sC_hi + zlo * sC_lo;
  int m0 = blockIdx.y * BM, n0 = blockIdx.x * BN;

  f32x4 acc[MT][NT] = {};

  for (int kt = 0; kt < K; kt += BK) {
    __syncthreads();
    // staging: instr t fills physical LDS slot eo; global col is the
    // swizzle-inverse (XOR is an involution). DMA dest stays lane-contiguous.
#pragma unroll
    for (int t = 0; t < ACH; t++) {
      int eo = (t * 256 + tid) * 8;
      int r = eo / BK, p = (eo % BK) >> 3;
      int c = (p ^ (r & 7)) << 3;
      GLOAD_LDS16(&Ab[(long)(m0 + r) * lda + kt + c], &As[eo]);
    }
#pragma unroll
    for (int t = 0; t < BCH; t++) {
      int eo = (t * 256 + tid) * 8;
      int r = eo / BK, p = (eo % BK) >> 3;
      int c = (p ^ (r & 7)) << 3;
      GLOAD_LDS16(&Bb[(long)(n0 + r) * ldb + kt + c], &Bs[eo]);
    }
    __syncthreads();
    bf16x8 af[KS][MT], bfr[KS][NT];
#pragma unroll
    for (int ks = 0; ks < KS; ks++) {
#pragma unroll
      for (int mt = 0; mt < MT; mt++) {
        int row = wm * MT * 16 + mt * 16 + l16;
        int p = (ks * 4 + quad) ^ (row & 7);
        af[ks][mt] = *(const bf16x8*)&As[row * BK + p * 8];
      }
#pragma unroll
      for (int nt = 0; nt < NT; nt++) {
        int row = wn * NT * 16 + nt * 16 + l16;
        int p = (ks * 4 + quad) ^ (row & 7);
        bfr[ks][nt] = *(const bf16x8*)&Bs[row * BK + p * 8];
      }
    }
#pragma unroll
    for (int ks = 0; ks < KS; ks++)
#pragma unroll
      for (int mt = 0; mt < MT; mt++)
#pragma unroll
        for (int nt = 0; nt < NT; nt++)
          acc[mt][nt] = __builtin_amdgcn_mfma_f32_16x16x32_bf16(
              af[ks][mt], bfr[ks][nt], acc[mt][nt], 0, 0, 0);
  }

  int gm = m0 + wm * MT * 16, gn = n0 + wn * NT * 16;
#pragma unroll
  for (int nt = 0; nt < NT; nt++) {
    int col = gn + nt * 16 + l16;
    float bv = (EPI != 0) ? bias[col] : 0.0f;
#pragma unroll
    for (int mt = 0; mt < MT; mt++) {
#pragma unroll
      for (int r = 0; r < 4; r++) {
        int row = gm + mt * 16 + quad * 4 + r;
        float v = acc[mt][nt][r] + bv;
        if (EPI == 2) {
          v = 0.5f * v * (1.0f + erff(v * 0.70710678118654752f));
        } else if (EPI == 1) {
          float rv = RBF16 ? (float)((const bf16*)resv)[(long)row * ldr + col]
                           : ((const float*)resv)[(long)row * ldr + col];
          v += rv;
        }
        if (CF32)
          ((float*)Cv)[coff + (long)row * ldc + col] = v;
        else
          ((bf16*)Cv)[coff + (long)row * ldc + col] = (bf16)v;
      }
    }
  }
}

extern "C" void kernel_launch(void* const* d_in, const int* in_sizes, int n_in,
                              void* d_out, int out_size, void* d_ws, size_t ws_size,
                              hipStream_t stream) {
  const float* src_q  = (const float*)d_in[0];
  const float* src_kv = (const float*)d_in[1];
  const float* gq     = (const float*)d_in[2];
  const float* bq     = (const float*)d_in[3];
  const float* gkv    = (const float*)d_in[4];
  const float* bkv    = (const float*)d_in[5];
  const float* Wq     = (const float*)d_in[6];
  const float* Wkv    = (const float*)d_in[7];
  const float* Wproj  = (const float*)d_in[8];
  const float* bproj  = (const float*)d_in[9];
  const float* gn     = (const float*)d_in[10];
  const float* bn     = (const float*)d_in[11];
  const float* W1     = (const float*)d_in[12];
  const float* b1     = (const float*)d_in[13];
  const float* W2     = (const float*)d_in[14];
  const float* b2     = (const float*)d_in[15];
  float* out = (float*)d_out;

  char* ws = (char*)d_ws;
  const long MB = 1024 * 1024;
  // peak 136MB (round-1 ran a 160MB layout without fault -> ws_size >= 160MB)
  bf16* Wq_t    = (bf16*)(ws + 0 * MB);    // [1024][1024]  2MB   (whole run)
  bf16* Wkv_t   = (bf16*)(ws + 2 * MB);    // [2048][1024]  4MB
  bf16* Wproj_t = (bf16*)(ws + 6 * MB);    // [1024][1024]  2MB
  bf16* W1_t    = (bf16*)(ws + 8 * MB);    // [4096][1024]  8MB
  bf16* W2_t    = (bf16*)(ws + 16 * MB);   // [1024][4096]  8MB  (ld = 4096!)
  bf16* qn      = (bf16*)(ws + 24 * MB);   // [4096][1024]  8MB   dead after Q GEMM
  bf16* kvn     = (bf16*)(ws + 32 * MB);   // [4096][1024]  8MB   dead after KV GEMM
  bf16* Qm      = (bf16*)(ws + 40 * MB);   // [4096][1024]  8MB   dead after last S GEMM
  bf16* KVm     = (bf16*)(ws + 48 * MB);   // [4096][2048] 16MB   dead after last S GEMM
  bf16* Vt      = (bf16*)(ws + 64 * MB);   // [64][64][1024] 8MB  dead after last PV GEMM
  bf16* Sbuf    = (bf16*)(ws + 72 * MB);   // 32x[1024][1024] 64MB per 2-batch pair
  bf16* xbuf    = (bf16*)(ws + 24 * MB);   // [4096][1024]  8MB   (reuses qn)
  float* tbuf   = (float*)(ws + 48 * MB);  // [4096][1024] 16MB fp32 (reuses KVm)
  bf16* sbuf    = (bf16*)(ws + 64 * MB);   // [4096][1024]  8MB   (reuses Vt)
  bf16* hbuf    = (bf16*)(ws + 72 * MB);   // [4096][4096] 32MB   (reuses Sbuf)

  // weight transposes (fp32 -> bf16)
  transpose_w<<<dim3(16, 16), 256, 0, stream>>>(Wq, Wq_t, 1024, 1024);
  transpose_w<<<dim3(32, 16), 256, 0, stream>>>(Wkv, Wkv_t, 1024, 2048);
  transpose_w<<<dim3(16, 16), 256, 0, stream>>>(Wproj, Wproj_t, 1024, 1024);
  transpose_w<<<dim3(64, 16), 256, 0, stream>>>(W1, W1_t, 1024, 4096);
  transpose_w<<<dim3(16, 64), 256, 0, stream>>>(W2, W2_t, 4096, 1024);

  // LayerNorms (fp32 -> bf16)
  ln_f32<<<4096, 256, 0, stream>>>(src_q, gq, bq, qn);
  ln_f32<<<4096, 256, 0, stream>>>(src_kv, gkv, bkv, kvn);

  // Q = qn @ Wq   (N=1024 -> BN=64 config, 512 blocks)
  gemm_t<128, 64, 64, 4, 1, 0, 0, 0><<<dim3(16, 32, 1), 256, 0, stream>>>(
      qn, 0, 0, 1024, Wq_t, 0, 0, 1024, Qm, 0, 0, 1024, 1024,
      nullptr, nullptr, 0);
  // KV = kvn @ Wkv  (N=2048, 128x128 tiles, 512 blocks)
  gemm_t<128, 128, 64, 2, 2, 0, 0, 0><<<dim3(16, 32, 1), 256, 0, stream>>>(
      kvn, 0, 0, 1024, Wkv_t, 0, 0, 1024, KVm, 0, 0, 2048, 1024,
      nullptr, nullptr, 0);
  extract_vt<<<dim3(16, 1, 64), 256, 0, stream>>>(KVm, Vt);

  // attention, 2 batches (32 heads) per chunk; z = b_local*16 + h
  for (int p = 0; p < 2; p++) {
    // S_bh = Q_bh @ K_bh^T  (K=64: single K-iteration)
    gemm_t<128, 128, 64, 2, 2, 0, 0, 0><<<dim3(8, 8, 32), 256, 0, stream>>>(
        Qm + (long)p * 2097152, 64, 1048576, 1024,
        KVm + (long)p * 4194304, 64, 2097152, 2048,
        Sbuf, 1048576, 16777216, 1024, 64,
        nullptr, nullptr, 0);
    softmax_rows<<<32768, 256, 0, stream>>>(Sbuf);
    // x_bh = P_bh @ V_bh  (N=64 exact tile: BM=64,BN=64 -> 512 blocks, no waste)
    gemm_t<64, 64, 64, 4, 1, 0, 0, 0><<<dim3(1, 16, 32), 256, 0, stream>>>(
        Sbuf, 1048576, 16777216, 1024,
        Vt + (long)p * 2097152, 65536, 1048576, 1024,
        xbuf + (long)p * 2097152, 64, 1048576, 1024, 1024,
        nullptr, nullptr, 0);
  }

  // tbuf = src_q + x @ Wproj + bproj   (fp32 out, N=1024 -> BN=64)
  gemm_t<128, 64, 64, 4, 1, 1, 1, 0><<<dim3(16, 32, 1), 256, 0, stream>>>(
      xbuf, 0, 0, 1024, Wproj_t, 0, 0, 1024, tbuf, 0, 0, 1024, 1024,
      bproj, src_q, 1024);
  // sbuf = LN(tbuf)  (bf16 out)
  ln_f32<<<4096, 256, 0, stream>>>(tbuf, gn, bn, sbuf);
  // hbuf = gelu(sbuf @ W1 + b1)  (bf16 out, N=4096)
  gemm_t<128, 128, 64, 2, 2, 2, 0, 0><<<dim3(32, 32, 1), 256, 0, stream>>>(
      sbuf, 0, 0, 1024, W1_t, 0, 0, 1024, hbuf, 0, 0, 4096, 1024,
      b1, nullptr, 0);
  // out = sbuf + hbuf @ W2 + b2  (fp32 out, N=1024 -> BN=64, K=4096; ldb=4096)
  gemm_t<128, 64, 64, 4, 1, 1, 1, 1><<<dim3(16, 32, 1), 256, 0, stream>>>(
      hbuf, 0, 0, 4096, W2_t, 0, 0, 4096, out, 0, 0, 1024, 4096,
      b2, sbuf, 1024);
}

// Round 7
// 437.004 us; speedup vs baseline: 1.7153x; 1.1362x over previous
//
#include <hip/hip_runtime.h>
#include <hip/hip_bf16.h>
#include <math.h>

typedef __bf16 bf16;
typedef __bf16 bf16x8 __attribute__((ext_vector_type(8)));
typedef float f32x4 __attribute__((ext_vector_type(4)));

#define SCALE 0.125f
#define L2E 1.4426950408889634f

// async global->LDS, 16B per lane. LDS dest must be wave-uniform base + lane*16.
#define GLOAD_LDS16(gptr, lptr)                                      \
  __builtin_amdgcn_global_load_lds(                                  \
      (const __attribute__((address_space(1))) void*)(gptr),         \
      (__attribute__((address_space(3))) void*)(lptr), 16, 0, 0)

// ---------------- row LayerNorm: fp32 in -> bf16 out, one block per row of 1024 ----------------
__global__ __launch_bounds__(256) void ln_f32(const float* __restrict__ x,
                                              const float* __restrict__ g,
                                              const float* __restrict__ b,
                                              bf16* __restrict__ y) {
  long base = (long)blockIdx.x * 1024;
  int tid = threadIdx.x;
  float v[4];
#pragma unroll
  for (int i = 0; i < 4; i++) v[i] = x[base + tid + i * 256];
  float s1 = v[0] + v[1] + v[2] + v[3];
  float s2 = v[0] * v[0] + v[1] * v[1] + v[2] * v[2] + v[3] * v[3];
#pragma unroll
  for (int off = 32; off; off >>= 1) {
    s1 += __shfl_xor(s1, off);
    s2 += __shfl_xor(s2, off);
  }
  __shared__ float aux[2][4];
  int wave = tid >> 6, lane = tid & 63;
  if (lane == 0) { aux[0][wave] = s1; aux[1][wave] = s2; }
  __syncthreads();
  float S1 = aux[0][0] + aux[0][1] + aux[0][2] + aux[0][3];
  float S2 = aux[1][0] + aux[1][1] + aux[1][2] + aux[1][3];
  float mean = S1 * (1.0f / 1024.0f);
  float var = S2 * (1.0f / 1024.0f) - mean * mean;
  float rs = rsqrtf(var + 1e-5f);
#pragma unroll
  for (int i = 0; i < 4; i++) {
    int c = tid + i * 256;
    y[base + c] = (bf16)(((v[i] - mean) * rs) * g[c] + b[c]);
  }
}

// ---------------- W[K][N] fp32 -> Wt[N][K] bf16 tiled transpose ----------------
__global__ __launch_bounds__(256) void transpose_w(const float* __restrict__ W,
                                                   bf16* __restrict__ Wt,
                                                   int K, int N) {
  __shared__ bf16 tile[64][66];
  int n0 = blockIdx.x * 64, k0 = blockIdx.y * 64;
  int c = threadIdx.x & 63, r4 = threadIdx.x >> 6;
#pragma unroll
  for (int i = 0; i < 16; i++)
    tile[i * 4 + r4][c] = (bf16)W[(long)(k0 + i * 4 + r4) * N + n0 + c];
  __syncthreads();
#pragma unroll
  for (int i = 0; i < 16; i++)
    Wt[(long)(n0 + i * 4 + r4) * K + k0 + c] = tile[c][i * 4 + r4];
}

// ------- extract V^T per (b,h): Vt[bh][d][n] = KV[b*1024+n][1024 + h*64 + d] (bf16) -------
__global__ __launch_bounds__(256) void extract_vt(const bf16* __restrict__ KV,
                                                  bf16* __restrict__ Vt) {
  __shared__ bf16 tile[64][66];
  int bh = blockIdx.z, b = bh >> 4, h = bh & 15;
  const bf16* src = KV + (long)b * 1024 * 2048 + 1024 + h * 64;
  bf16* dst = Vt + (long)bh * 64 * 1024;
  int n0 = blockIdx.x * 64;
  int c = threadIdx.x & 63, r4 = threadIdx.x >> 6;
#pragma unroll
  for (int i = 0; i < 16; i++)
    tile[i * 4 + r4][c] = src[(long)(n0 + i * 4 + r4) * 2048 + c];
  __syncthreads();
#pragma unroll
  for (int i = 0; i < 16; i++)
    dst[(long)(i * 4 + r4) * 1024 + n0 + c] = tile[c][i * 4 + r4];
}

// ---------------- fused flash attention ----------------
// grid (8 q-tiles, 64 bh). Per block: Q-tile [128][64] resident; loop 8
// K-chunks of 128: S=Q@K^T (MFMA) -> online softmax -> P via LDS (C-layout ->
// A-layout, m120 pattern) -> O += P@V (MFMA, B = V^T chunk [64][128]).
// Both SCALE factors folded: one into exp arg, one into epilogue /l.
// Wave w owns rows [w*32, w*32+32); row stats reduce over l16 (xor 1,2,4,8).
__global__ __launch_bounds__(256) void attn_fused(
    const bf16* __restrict__ Q,   // [4096][1024]
    const bf16* __restrict__ KV,  // [4096][2048], K at col h*64
    const bf16* __restrict__ Vt,  // [64 bh][64 d][1024 n]
    bf16* __restrict__ X) {       // [4096][1024]
  __shared__ __align__(16) bf16 Qs[128 * 64];
  __shared__ __align__(16) bf16 Ks[128 * 64];
  __shared__ __align__(16) bf16 Vs[64 * 128];
  __shared__ __align__(16) bf16 Ps[128 * 128];
  int tid = threadIdx.x, wave = tid >> 6, lane = tid & 63;
  int quad = lane >> 4, l16 = lane & 15;
  int bh = blockIdx.y, b = bh >> 4, h = bh & 15;
  const bf16* Qb = Q + (long)b * 1048576 + h * 64;    // ld 1024
  const bf16* Kb = KV + (long)b * 2097152 + h * 64;   // ld 2048
  const bf16* Vb = Vt + (long)bh * 65536;             // ld 1024
  bf16* Xb = X + (long)b * 1048576 + h * 64;          // ld 1024
  int q0 = blockIdx.x * 128;

  // stage Q tile [128][64], XOR-swizzled (8 chunks/row), once
#pragma unroll
  for (int t = 0; t < 4; t++) {
    int eo = (t * 256 + tid) * 8;
    int r = eo >> 6, p = (eo & 63) >> 3;
    int c = (p ^ (r & 7)) << 3;
    GLOAD_LDS16(&Qb[(long)(q0 + r) * 1024 + c], &Qs[eo]);
  }

  float m_run[2][4], l_run[2][4];
#pragma unroll
  for (int mt = 0; mt < 2; mt++)
#pragma unroll
    for (int r = 0; r < 4; r++) { m_run[mt][r] = -1e30f; l_run[mt][r] = 0.0f; }
  f32x4 acc_o[2][4] = {};

  for (int kc = 0; kc < 8; kc++) {
    __syncthreads();
    // stage K chunk [128 n][64 d] and V^T chunk [64 d][128 n]
#pragma unroll
    for (int t = 0; t < 4; t++) {
      int eo = (t * 256 + tid) * 8;
      int r = eo >> 6, p = (eo & 63) >> 3;
      int c = (p ^ (r & 7)) << 3;
      GLOAD_LDS16(&Kb[(long)(kc * 128 + r) * 2048 + c], &Ks[eo]);
    }
#pragma unroll
    for (int t = 0; t < 4; t++) {
      int eo = (t * 256 + tid) * 8;
      int r = eo >> 7, p = (eo & 127) >> 3;
      int c = (p ^ (r & 7)) << 3;
      GLOAD_LDS16(&Vb[(long)r * 1024 + kc * 128 + c], &Vs[eo]);
    }
    __syncthreads();

    // S-tile: wave rows [wave*32,+32) x cols 0..127
    f32x4 s[2][8] = {};
    bf16x8 aq[2][2];
#pragma unroll
    for (int ks = 0; ks < 2; ks++)
#pragma unroll
      for (int mt = 0; mt < 2; mt++) {
        int row = wave * 32 + mt * 16 + l16;
        int p = (ks * 4 + quad) ^ (row & 7);
        aq[ks][mt] = *(const bf16x8*)&Qs[row * 64 + p * 8];
      }
#pragma unroll
    for (int ks = 0; ks < 2; ks++)
#pragma unroll
      for (int nt = 0; nt < 8; nt++) {
        int row = nt * 16 + l16;
        int p = (ks * 4 + quad) ^ (row & 7);
        bf16x8 bk = *(const bf16x8*)&Ks[row * 64 + p * 8];
#pragma unroll
        for (int mt = 0; mt < 2; mt++)
          s[mt][nt] = __builtin_amdgcn_mfma_f32_16x16x32_bf16(
              aq[ks][mt], bk, s[mt][nt], 0, 0, 0);
      }

    // online softmax (scaled domain)
#pragma unroll
    for (int mt = 0; mt < 2; mt++) {
#pragma unroll
      for (int r = 0; r < 4; r++) {
        float mx = -1e30f;
#pragma unroll
        for (int nt = 0; nt < 8; nt++) {
          float sv = s[mt][nt][r] * SCALE;
          s[mt][nt][r] = sv;
          mx = fmaxf(mx, sv);
        }
#pragma unroll
        for (int off = 1; off < 16; off <<= 1) mx = fmaxf(mx, __shfl_xor(mx, off));
        float m_new = fmaxf(m_run[mt][r], mx);
        float alpha = exp2f((m_run[mt][r] - m_new) * L2E);
        m_run[mt][r] = m_new;
        float rs = 0.0f;
#pragma unroll
        for (int nt = 0; nt < 8; nt++) {
          float pv = exp2f((s[mt][nt][r] - m_new) * L2E);
          s[mt][nt][r] = pv;
          rs += pv;
        }
#pragma unroll
        for (int off = 1; off < 16; off <<= 1) rs += __shfl_xor(rs, off);
        l_run[mt][r] = l_run[mt][r] * alpha + rs;
#pragma unroll
        for (int nt = 0; nt < 4; nt++) acc_o[mt][nt][r] *= alpha;
      }
    }

    // P: C-layout regs -> LDS (wave-private rows), 16-chunk XOR swizzle
#pragma unroll
    for (int mt = 0; mt < 2; mt++)
#pragma unroll
      for (int nt = 0; nt < 8; nt++)
#pragma unroll
        for (int r = 0; r < 4; r++) {
          int row = wave * 32 + mt * 16 + quad * 4 + r;
          int col = nt * 16 + l16;
          int pc = (col >> 3) ^ (row & 7);
          Ps[row * 128 + pc * 8 + (col & 7)] = (bf16)s[mt][nt][r];
        }
    // in-wave write->read; compiler inserts lgkmcnt waits

    // PV: A = Ps rows [wave*32,+32) x 128 k; B = Vs [64 d][128 k]
    bf16x8 ap[4][2];
#pragma unroll
    for (int ks = 0; ks < 4; ks++)
#pragma unroll
      for (int mt = 0; mt < 2; mt++) {
        int row = wave * 32 + mt * 16 + l16;
        int p = (ks * 4 + quad) ^ (row & 7);
        ap[ks][mt] = *(const bf16x8*)&Ps[row * 128 + p * 8];
      }
#pragma unroll
    for (int ks = 0; ks < 4; ks++)
#pragma unroll
      for (int nt = 0; nt < 4; nt++) {
        int row = nt * 16 + l16;
        int p = (ks * 4 + quad) ^ (row & 7);
        bf16x8 bv = *(const bf16x8*)&Vs[row * 128 + p * 8];
#pragma unroll
        for (int mt = 0; mt < 2; mt++)
          acc_o[mt][nt] = __builtin_amdgcn_mfma_f32_16x16x32_bf16(
              ap[ks][mt], bv, acc_o[mt][nt], 0, 0, 0);
      }
  }

  // epilogue: x = acc_o * SCALE / l  (second faithful SCALE)
#pragma unroll
  for (int mt = 0; mt < 2; mt++)
#pragma unroll
    for (int nt = 0; nt < 4; nt++)
#pragma unroll
      for (int r = 0; r < 4; r++) {
        int row = q0 + wave * 32 + mt * 16 + quad * 4 + r;
        int col = nt * 16 + l16;
        Xb[(long)row * 1024 + col] =
            (bf16)(acc_o[mt][nt][r] * SCALE / l_run[mt][r]);
      }
}

// ---------------- templated C = A @ Bt^T (+epilogue) ----------------
// A[M,K] bf16 (lda), Bt[N,K] bf16 (ldb). z = (z>>4)*hi + (z&15)*lo strides.
// LDS XOR-swizzled (16B chunk p of row r holds logical chunk p^(r&7)).
// EPI: 0 = store bf16; 1 = acc+bias+res (CF32 fp32 C; RBF16 bf16 res);
//      2 = gelu(acc+bias) -> bf16
template <int BM, int BN, int BK, int WR, int WC, int EPI, int CF32, int RBF16>
__global__ __launch_bounds__(256) void gemm_t(
    const bf16* __restrict__ A, long sA_lo, long sA_hi, int lda,
    const bf16* __restrict__ B, long sB_lo, long sB_hi, int ldb,
    void* __restrict__ Cv, long sC_lo, long sC_hi, int ldc,
    int K,
    const float* __restrict__ bias,
    const void* __restrict__ resv, int ldr) {
  constexpr int MT = BM / (16 * WR);
  constexpr int NT = BN / (16 * WC);
  constexpr int KS = BK / 32;
  constexpr int ACH = BM * BK / 2048;
  constexpr int BCH = BN * BK / 2048;
  __shared__ __align__(16) bf16 As[BM * BK];
  __shared__ __align__(16) bf16 Bs[BN * BK];
  int tid = threadIdx.x;
  int wave = tid >> 6, lane = tid & 63;
  int wm = wave / WC, wn = wave % WC;
  int quad = lane >> 4, l16 = lane & 15;
  int zhi = blockIdx.z >> 4, zlo = blockIdx.z & 15;
  const bf16* Ab = A + zhi * sA_hi + zlo * sA_lo;
  const bf16* Bb = B + zhi * sB_hi + zlo * sB_lo;
  long coff = zhi * sC_hi + zlo * sC_lo;
  int m0 = blockIdx.y * BM, n0 = blockIdx.x * BN;

  f32x4 acc[MT][NT] = {};

  for (int kt = 0; kt < K; kt += BK) {
    __syncthreads();
#pragma unroll
    for (int t = 0; t < ACH; t++) {
      int eo = (t * 256 + tid) * 8;
      int r = eo / BK, p = (eo % BK) >> 3;
      int c = (p ^ (r & 7)) << 3;
      GLOAD_LDS16(&Ab[(long)(m0 + r) * lda + kt + c], &As[eo]);
    }
#pragma unroll
    for (int t = 0; t < BCH; t++) {
      int eo = (t * 256 + tid) * 8;
      int r = eo / BK, p = (eo % BK) >> 3;
      int c = (p ^ (r & 7)) << 3;
      GLOAD_LDS16(&Bb[(long)(n0 + r) * ldb + kt + c], &Bs[eo]);
    }
    __syncthreads();
    bf16x8 af[KS][MT], bfr[KS][NT];
#pragma unroll
    for (int ks = 0; ks < KS; ks++) {
#pragma unroll
      for (int mt = 0; mt < MT; mt++) {
        int row = wm * MT * 16 + mt * 16 + l16;
        int p = (ks * 4 + quad) ^ (row & 7);
        af[ks][mt] = *(const bf16x8*)&As[row * BK + p * 8];
      }
#pragma unroll
      for (int nt = 0; nt < NT; nt++) {
        int row = wn * NT * 16 + nt * 16 + l16;
        int p = (ks * 4 + quad) ^ (row & 7);
        bfr[ks][nt] = *(const bf16x8*)&Bs[row * BK + p * 8];
      }
    }
#pragma unroll
    for (int ks = 0; ks < KS; ks++)
#pragma unroll
      for (int mt = 0; mt < MT; mt++)
#pragma unroll
        for (int nt = 0; nt < NT; nt++)
          acc[mt][nt] = __builtin_amdgcn_mfma_f32_16x16x32_bf16(
              af[ks][mt], bfr[ks][nt], acc[mt][nt], 0, 0, 0);
  }

  int gm = m0 + wm * MT * 16, gn = n0 + wn * NT * 16;
#pragma unroll
  for (int nt = 0; nt < NT; nt++) {
    int col = gn + nt * 16 + l16;
    float bv = (EPI != 0) ? bias[col] : 0.0f;
#pragma unroll
    for (int mt = 0; mt < MT; mt++) {
#pragma unroll
      for (int r = 0; r < 4; r++) {
        int row = gm + mt * 16 + quad * 4 + r;
        float v = acc[mt][nt][r] + bv;
        if (EPI == 2) {
          v = 0.5f * v * (1.0f + erff(v * 0.70710678118654752f));
        } else if (EPI == 1) {
          float rv = RBF16 ? (float)((const bf16*)resv)[(long)row * ldr + col]
                           : ((const float*)resv)[(long)row * ldr + col];
          v += rv;
        }
        if (CF32)
          ((float*)Cv)[coff + (long)row * ldc + col] = v;
        else
          ((bf16*)Cv)[coff + (long)row * ldc + col] = (bf16)v;
      }
    }
  }
}

extern "C" void kernel_launch(void* const* d_in, const int* in_sizes, int n_in,
                              void* d_out, int out_size, void* d_ws, size_t ws_size,
                              hipStream_t stream) {
  const float* src_q  = (const float*)d_in[0];
  const float* src_kv = (const float*)d_in[1];
  const float* gq     = (const float*)d_in[2];
  const float* bq     = (const float*)d_in[3];
  const float* gkv    = (const float*)d_in[4];
  const float* bkv    = (const float*)d_in[5];
  const float* Wq     = (const float*)d_in[6];
  const float* Wkv    = (const float*)d_in[7];
  const float* Wproj  = (const float*)d_in[8];
  const float* bproj  = (const float*)d_in[9];
  const float* gn     = (const float*)d_in[10];
  const float* bn     = (const float*)d_in[11];
  const float* W1     = (const float*)d_in[12];
  const float* b1     = (const float*)d_in[13];
  const float* W2     = (const float*)d_in[14];
  const float* b2     = (const float*)d_in[15];
  float* out = (float*)d_out;

  char* ws = (char*)d_ws;
  const long MB = 1024 * 1024;
  bf16* Wq_t    = (bf16*)(ws + 0 * MB);    // [1024][1024]  2MB   (whole run)
  bf16* Wkv_t   = (bf16*)(ws + 2 * MB);    // [2048][1024]  4MB
  bf16* Wproj_t = (bf16*)(ws + 6 * MB);    // [1024][1024]  2MB
  bf16* W1_t    = (bf16*)(ws + 8 * MB);    // [4096][1024]  8MB
  bf16* W2_t    = (bf16*)(ws + 16 * MB);   // [1024][4096]  8MB  (ld = 4096!)
  bf16* qn      = (bf16*)(ws + 24 * MB);   // [4096][1024]  8MB   dead after Q GEMM
  bf16* kvn     = (bf16*)(ws + 32 * MB);   // [4096][1024]  8MB   dead after KV GEMM
  bf16* Qm      = (bf16*)(ws + 40 * MB);   // [4096][1024]  8MB   dead after attn
  bf16* KVm     = (bf16*)(ws + 48 * MB);   // [4096][2048] 16MB   dead after attn
  bf16* Vt      = (bf16*)(ws + 64 * MB);   // [64][64][1024] 8MB  dead after attn
  bf16* xbuf    = (bf16*)(ws + 24 * MB);   // [4096][1024]  8MB   (reuses qn)
  float* tbuf   = (float*)(ws + 48 * MB);  // [4096][1024] 16MB fp32 (reuses KVm)
  bf16* sbuf    = (bf16*)(ws + 64 * MB);   // [4096][1024]  8MB   (reuses Vt)
  bf16* hbuf    = (bf16*)(ws + 72 * MB);   // [4096][4096] 32MB

  // weight transposes (fp32 -> bf16)
  transpose_w<<<dim3(16, 16), 256, 0, stream>>>(Wq, Wq_t, 1024, 1024);
  transpose_w<<<dim3(32, 16), 256, 0, stream>>>(Wkv, Wkv_t, 1024, 2048);
  transpose_w<<<dim3(16, 16), 256, 0, stream>>>(Wproj, Wproj_t, 1024, 1024);
  transpose_w<<<dim3(64, 16), 256, 0, stream>>>(W1, W1_t, 1024, 4096);
  transpose_w<<<dim3(16, 64), 256, 0, stream>>>(W2, W2_t, 4096, 1024);

  // LayerNorms (fp32 -> bf16)
  ln_f32<<<4096, 256, 0, stream>>>(src_q, gq, bq, qn);
  ln_f32<<<4096, 256, 0, stream>>>(src_kv, gkv, bkv, kvn);

  // Q = qn @ Wq   (N=1024 -> BN=64 config, 512 blocks)
  gemm_t<128, 64, 64, 4, 1, 0, 0, 0><<<dim3(16, 32, 1), 256, 0, stream>>>(
      qn, 0, 0, 1024, Wq_t, 0, 0, 1024, Qm, 0, 0, 1024, 1024,
      nullptr, nullptr, 0);
  // KV = kvn @ Wkv  (N=2048, 128x128 tiles, 512 blocks)
  gemm_t<128, 128, 64, 2, 2, 0, 0, 0><<<dim3(16, 32, 1), 256, 0, stream>>>(
      kvn, 0, 0, 1024, Wkv_t, 0, 0, 1024, KVm, 0, 0, 2048, 1024,
      nullptr, nullptr, 0);
  extract_vt<<<dim3(16, 1, 64), 256, 0, stream>>>(KVm, Vt);

  // fused flash attention: 8 q-tiles x 64 bh, 512 blocks (2/CU at 80KB LDS)
  attn_fused<<<dim3(8, 64), 256, 0, stream>>>(Qm, KVm, Vt, xbuf);

  // tbuf = src_q + x @ Wproj + bproj   (fp32 out, N=1024 -> BN=64)
  gemm_t<128, 64, 64, 4, 1, 1, 1, 0><<<dim3(16, 32, 1), 256, 0, stream>>>(
      xbuf, 0, 0, 1024, Wproj_t, 0, 0, 1024, tbuf, 0, 0, 1024, 1024,
      bproj, src_q, 1024);
  // sbuf = LN(tbuf)  (bf16 out)
  ln_f32<<<4096, 256, 0, stream>>>(tbuf, gn, bn, sbuf);
  // hbuf = gelu(sbuf @ W1 + b1)  (bf16 out, N=4096)
  gemm_t<128, 128, 64, 2, 2, 2, 0, 0><<<dim3(32, 32, 1), 256, 0, stream>>>(
      sbuf, 0, 0, 1024, W1_t, 0, 0, 1024, hbuf, 0, 0, 4096, 1024,
      b1, nullptr, 0);
  // out = sbuf + hbuf @ W2 + b2  (fp32 out, N=1024 -> BN=64, K=4096; ldb=4096)
  gemm_t<128, 64, 64, 4, 1, 1, 1, 1><<<dim3(16, 32, 1), 256, 0, stream>>>(
      hbuf, 0, 0, 4096, W2_t, 0, 0, 4096, out, 0, 0, 1024, 4096,
      b2, sbuf, 1024);
}